// Round 10
// baseline (384.087 us; speedup 1.0000x reference)
//
#include <hip/hip_runtime.h>
#include <vector>
#include <algorithm>
#include <utility>

typedef unsigned long long u64;
typedef unsigned int u32;

#define NTRIP 110592              // 48^3 distinct (c0,c1,c2)
#define IDXBITS 21
#define IMASK ((1u << IDXBITS) - 1)
#define NCOARSE 512               // top 9 bits of 23-bit key
#define CAPB 5632                 // per-bucket padded capacity (mean 3906, +27 sigma)
#define NSUB 4096                 // K2 sub-bins (key bits 2..13)
#define NWORDS 131072             // 2^23 / 64 bitmap words
#define K1_E 8

// ======== host-side: rank table for the 110,592 triple-hashes ========
// full hash = fnv3p(c0,c1,c2) ^ c3 (c3 < 64 flips only low 6 bits).
// rank48[tau] = (rank_of_hash << 6) | (hash & 63); point key = rank48[tau]^c3 (23 bits)
static u32 g_rank48[NTRIP];
namespace {
struct RankInit {
    RankInit() {
        std::vector<std::pair<u64, u32>> v(NTRIP);
        for (u32 t = 0; t < NTRIP; t++) {
            u64 h = 14695981039346656037ull;
            const u64 P = 1099511628211ull;
            h *= P; h ^= (u64)(t / 2304);
            h *= P; h ^= (u64)((t % 2304) / 48);
            h *= P; h ^= (u64)(t % 48);
            h *= P;
            v[t] = {h, t};
        }
        std::sort(v.begin(), v.end());
        for (u32 p = 0; p < NTRIP; p++)
            g_rank48[v[p].second] = (p << 6) | (u32)(v[p].first & 63ull);
    }
};
static RankInit g_rank_init;
}

__global__ void k_invrank(const u32* __restrict__ rank48, u32* __restrict__ invrank) {
    int tau = blockIdx.x * blockDim.x + threadIdx.x;
    if (tau >= NTRIP) return;
    u32 r = rank48[tau];
    invrank[r >> 6] = ((u32)tau << 6) | (r & 63u);
}

// ======== K1: keys + bitmap + padded coarse scatter (fused) ========
__global__ void k_hashscatter(const int* __restrict__ coords, const u32* __restrict__ rank48,
                              u32* __restrict__ fill, u64* __restrict__ bitmap,
                              u64* __restrict__ sortedp, u32* __restrict__ pkey, int N) {
    __shared__ u32 lh[NCOARSE], lclaim[NCOARSE], lcnt[NCOARSE];
    int tid = threadIdx.x;
    for (int d = tid; d < NCOARSE; d += 256) { lh[d] = 0; lcnt[d] = 0; }
    __syncthreads();
    int base = blockIdx.x * (256 * K1_E);
    u32 kk[K1_E];
    bool val[K1_E];
#pragma unroll
    for (int k = 0; k < K1_E; k++) {
        int i = base + k * 256 + tid;
        val[k] = i < N;
        if (val[k]) {
            int4 c = ((const int4*)coords)[i];
            u32 tau = (u32)c.x * 2304u + (u32)c.y * 48u + (u32)c.z;
            u32 key = rank48[tau] ^ (u32)c.w;
            kk[k] = key;
            pkey[i] = key;
            atomicOr(&bitmap[key >> 6], 1ull << (key & 63u));
            atomicAdd(&lh[key >> 14], 1u);
        }
    }
    __syncthreads();
    for (int d = tid; d < NCOARSE; d += 256) {
        u32 c = lh[d];
        lclaim[d] = c ? atomicAdd(&fill[d], c) : 0u;
    }
    __syncthreads();
#pragma unroll
    for (int k = 0; k < K1_E; k++) {
        if (val[k]) {
            int i = base + k * 256 + tid;
            u32 d = kk[k] >> 14;
            u32 r = lclaim[d] + atomicAdd(&lcnt[d], 1u);
            if (r < CAPB) sortedp[(size_t)d * CAPB + r] = ((u64)kk[k] << IDXBITS) | (u32)i;
        }
    }
}

// ======== K1.5: per-word distinct-rank prefix within each bucket ========
__global__ void k_wprefix(const u64* __restrict__ bitmap, u32* __restrict__ wprefix,
                          u32* __restrict__ dtotal) {
    __shared__ u32 s[256];
    int t = threadIdx.x, b = blockIdx.x;
    int w = b * 256 + t;
    u32 c = (u32)__popcll(bitmap[w]);
    s[t] = c;
    __syncthreads();
    for (int off = 1; off < 256; off <<= 1) {
        u32 v = (t >= off) ? s[t - off] : 0u;
        __syncthreads();
        s[t] += v;
        __syncthreads();
    }
    wprefix[w] = s[t] - c;
    if (t == 255) dtotal[b] = s[255];
}

// ======== K1.6: scan fills -> pointbase; scan dtotals -> gidbase; num_voxels ========
__global__ void k_meta(const u32* __restrict__ fill, const u32* __restrict__ dtotal,
                       u32* __restrict__ pointbase, u32* __restrict__ gidbase,
                       u32* __restrict__ nvslot) {
    __shared__ u32 s[256];
    int t = threadIdx.x;
    u32 f0 = fill[2 * t], f1 = fill[2 * t + 1];
    u32 a = f0 < CAPB ? f0 : CAPB, b = f1 < CAPB ? f1 : CAPB;
    u32 sum = a + b;
    s[t] = sum;
    __syncthreads();
    for (int off = 1; off < 256; off <<= 1) {
        u32 v = (t >= off) ? s[t - off] : 0u;
        __syncthreads();
        s[t] += v;
        __syncthreads();
    }
    u32 tb = s[t] - sum;
    pointbase[2 * t] = tb;
    pointbase[2 * t + 1] = tb + a;
    __syncthreads();
    u32 a2 = dtotal[2 * t], b2 = dtotal[2 * t + 1];
    u32 sum2 = a2 + b2;
    s[t] = sum2;
    __syncthreads();
    for (int off = 1; off < 256; off <<= 1) {
        u32 v = (t >= off) ? s[t - off] : 0u;
        __syncthreads();
        s[t] += v;
        __syncthreads();
    }
    u32 tb2 = s[t] - sum2;
    gidbase[2 * t] = tb2;
    gidbase[2 * t + 1] = tb2 + a2;
    if (t == 255) nvslot[0] = s[255];
}

// ======== K2: per-bucket LDS counting sort + voxel meta emit (fused) ========
__global__ __launch_bounds__(256) void k_sortbucket(const u32* __restrict__ fill,
                                                    const u32* __restrict__ pointbase,
                                                    const u32* __restrict__ gidbase,
                                                    const u64* __restrict__ sortedp,
                                                    u32* __restrict__ mlist,
                                                    u64* __restrict__ voxmeta) {
    __shared__ u64 lout[CAPB];
    __shared__ u32 lbins[NSUB * 2];   // lbase | lcnt; later reused as starts
    __shared__ u32 lpart[256];
    int tid = threadIdx.x, b = blockIdx.x;
    u32 fb = fill[b];
    int s = (int)(fb < CAPB ? fb : CAPB);
    if (s == 0) return;
    u32 pb = pointbase[b], gb = gidbase[b];
    size_t base = (size_t)b * CAPB;
    for (int d = tid; d < NSUB; d += 256) { lbins[d] = 0; lbins[NSUB + d] = 0; }
    __syncthreads();
    u64 p[22];
#pragma unroll
    for (int k = 0; k < 22; k++) {
        int e = k * 256 + tid;
        if (e < s) {
            p[k] = sortedp[base + e];
            atomicAdd(&lbins[(u32)(p[k] >> 23) & 0xFFFu], 1u);
        }
    }
    __syncthreads();
    u32 my[16];
    u32 run = 0;
#pragma unroll
    for (int k = 0; k < 16; k++) { my[k] = lbins[tid * 16 + k]; run += my[k]; }
    lpart[tid] = run;
    __syncthreads();
    for (int off = 1; off < 256; off <<= 1) {
        u32 v = (tid >= off) ? lpart[tid - off] : 0u;
        __syncthreads();
        lpart[tid] += v;
        __syncthreads();
    }
    u32 tb = lpart[tid] - run;
#pragma unroll
    for (int k = 0; k < 16; k++) { u32 c = my[k]; lbins[tid * 16 + k] = tb; tb += c; }
    __syncthreads();
#pragma unroll
    for (int k = 0; k < 22; k++) {
        int e = k * 256 + tid;
        if (e < s) {
            u32 d = (u32)(p[k] >> 23) & 0xFFFu;
            u32 slot = lbins[d] + atomicAdd(&lbins[NSUB + d], 1u);
            lout[slot] = p[k];
        }
    }
    __syncthreads();
    // cleanup: insertion sort on full u64 inside each sub-bin (avg ~1 elem)
    for (int d = tid; d < NSUB; d += 256) {
        u32 c = lbins[NSUB + d];
        if (c >= 2) {
            u32 st = lbins[d];
            for (u32 j = st + 1; j < st + c; j++) {
                u64 pj = lout[j];
                int k2 = (int)j - 1;
                while (k2 >= (int)st && lout[k2] > pj) { lout[k2 + 1] = lout[k2]; k2--; }
                lout[k2 + 1] = pj;
            }
        }
    }
    __syncthreads();
    // coalesced mlist write (idx only)
    for (int e = tid; e < s; e += 256) mlist[pb + e] = (u32)lout[e] & IMASK;
    // chunked boundary flags
    int per = (s + 255) / 256;
    int e0 = tid * per;
    int e1 = e0 + per; if (e1 > s) e1 = s;
    u32 cnt = 0;
    for (int e = e0; e < e1; e++) {
        u32 key = (u32)(lout[e] >> IDXBITS);
        u32 pk = e ? (u32)(lout[e - 1] >> IDXBITS) : 0xFFFFFFFFu;
        cnt += (key != pk) ? 1u : 0u;
    }
    lpart[tid] = cnt;
    __syncthreads();
    for (int off = 1; off < 256; off <<= 1) {
        u32 v = (tid >= off) ? lpart[tid - off] : 0u;
        __syncthreads();
        lpart[tid] += v;
        __syncthreads();
    }
    u32 dcnt = lpart[255];
    u32 g = lpart[tid] - cnt;
    __syncthreads();                 // all reads of lbins (sort phase) done; reuse as starts
    u32* starts = lbins;             // dcnt <= s <= 5632 < 8192
    for (int e = e0; e < e1; e++) {
        u32 key = (u32)(lout[e] >> IDXBITS);
        u32 pk = e ? (u32)(lout[e - 1] >> IDXBITS) : 0xFFFFFFFFu;
        if (key != pk) starts[g++] = (u32)e;
    }
    __syncthreads();
    for (u32 L = tid; L < dcnt; L += 256) {
        u32 st = starts[L];
        u32 en = (L + 1 < dcnt) ? starts[L + 1] : (u32)s;
        u32 key = (u32)(lout[st] >> IDXBITS);
        u32 c = en - st; if (c > 511u) c = 511u;
        voxmeta[gb + L] = (u64)(pb + st) | ((u64)key << 32) | ((u64)c << 55);
    }
}

// ======== K3: v2p via bitmap popcount rank (coalesced write) ========
__global__ void k_v2p(const u32* __restrict__ pkey, const u64* __restrict__ bitmap,
                      const u32* __restrict__ wprefix, const u32* __restrict__ gidbase,
                      float* __restrict__ v2p, int N) {
    int i = blockIdx.x * blockDim.x + threadIdx.x;
    if (i >= N) return;
    u32 kk = pkey[i];
    u64 word = bitmap[kk >> 6];
    u32 gid = gidbase[kk >> 14] + wprefix[kk >> 6] +
              (u32)__popcll(word & ((1ull << (kk & 63u)) - 1ull));
    v2p[i] = (float)gid;
}

// ======== K4: per-voxel outputs + padding zeros ========
__global__ void k_vox(const u64* __restrict__ voxmeta, const u32* __restrict__ mlist,
                      const u32* __restrict__ invrank, const float* __restrict__ feats,
                      const u32* __restrict__ nvslot, float* __restrict__ vox_feats,
                      float* __restrict__ vox_coords, float* __restrict__ nvox, int N) {
    int t = blockIdx.x * blockDim.x + threadIdx.x;
    if (t >= N) return;
    u32 nv = nvslot[0];
    if (t == 0) nvox[0] = (float)nv;
    if ((u32)t >= nv) {
        float4 z = {0, 0, 0, 0};
        float4* vf = (float4*)(vox_feats + (size_t)t * 16);
        vf[0] = z; vf[1] = z; vf[2] = z; vf[3] = z;
        *(float4*)(vox_coords + (size_t)t * 4) = z;
        return;
    }
    u64 m = voxmeta[t];
    u32 st = (u32)m;
    u32 kk = (u32)(m >> 32) & 0x7FFFFFu;
    u32 c = (u32)(m >> 55);
    float4 a0 = {0, 0, 0, 0}, a1 = {0, 0, 0, 0}, a2 = {0, 0, 0, 0}, a3 = {0, 0, 0, 0};
    for (u32 e = st; e < st + c; e++) {
        u32 idx = mlist[e];
        const float4* f = (const float4*)(feats + (size_t)idx * 16);
        float4 v0 = f[0], v1 = f[1], v2 = f[2], v3 = f[3];
        a0.x += v0.x; a0.y += v0.y; a0.z += v0.z; a0.w += v0.w;
        a1.x += v1.x; a1.y += v1.y; a1.z += v1.z; a1.w += v1.w;
        a2.x += v2.x; a2.y += v2.y; a2.z += v2.z; a2.w += v2.w;
        a3.x += v3.x; a3.y += v3.y; a3.z += v3.z; a3.w += v3.w;
    }
    float fc = (float)c;
    float4* vf = (float4*)(vox_feats + (size_t)t * 16);
    vf[0] = make_float4(a0.x / fc, a0.y / fc, a0.z / fc, a0.w / fc);
    vf[1] = make_float4(a1.x / fc, a1.y / fc, a1.z / fc, a1.w / fc);
    vf[2] = make_float4(a2.x / fc, a2.y / fc, a2.z / fc, a2.w / fc);
    vf[3] = make_float4(a3.x / fc, a3.y / fc, a3.z / fc, a3.w / fc);
    u32 iv = invrank[kk >> 6];
    u32 tau = iv >> 6;
    u32 c3 = (kk ^ iv) & 63u;
    *(float4*)(vox_coords + (size_t)t * 4) =
        make_float4((float)(tau / 2304u), (float)((tau % 2304u) / 48u),
                    (float)(tau % 48u), (float)c3);
}

extern "C" void kernel_launch(void* const* d_in, const int* in_sizes, int n_in,
                              void* d_out, int out_size, void* d_ws, size_t ws_size,
                              hipStream_t stream) {
    const int* coords = (const int*)d_in[0];
    const float* feats = (const float*)d_in[1];
    int N = in_sizes[0] / 4;

    float* out = (float*)d_out;
    float* vox_feats = out;                      // N*16
    float* vox_coords = out + (size_t)N * 16;    // N*4
    float* v2p = vox_coords + (size_t)N * 4;     // N
    float* nvox = v2p + (size_t)N;               // 1

    char* w = (char*)d_ws;
    u64* sortedp = (u64*)w;    w += (size_t)NCOARSE * CAPB * 8;  // 23.1 MB
    u32* pkey = (u32*)w;       w += (size_t)N * 4;               // 8 MB
    u32* mlist = (u32*)w;      w += (size_t)N * 4;               // 8 MB
    u64* voxmeta = (u64*)w;    w += (size_t)N * 8;               // 16 MB
    u64* bitmap = (u64*)w;     w += (size_t)NWORDS * 8;          // 1 MB
    u32* fill = (u32*)w;       w += NCOARSE * 4;                 // (memset with bitmap)
    u32* wprefix = (u32*)w;    w += (size_t)NWORDS * 4;          // 512 KB
    u32* dtotal = (u32*)w;     w += NCOARSE * 4;
    u32* pointbase = (u32*)w;  w += NCOARSE * 4;
    u32* gidbase = (u32*)w;    w += NCOARSE * 4;
    u32* rank48_d = (u32*)w;   w += (size_t)NTRIP * 4;
    u32* invrank_d = (u32*)w;  w += (size_t)NTRIP * 4;
    u32* nvslot = (u32*)w;     w += 256;

    hipMemcpyAsync(rank48_d, g_rank48, sizeof(g_rank48), hipMemcpyHostToDevice, stream);
    hipMemsetAsync(bitmap, 0, (size_t)NWORDS * 8 + NCOARSE * 4, stream);  // bitmap + fill

    int blocksT = (NTRIP + 255) / 256;
    int blocksK1 = (N + 256 * K1_E - 1) / (256 * K1_E);
    int blocksN = (N + 255) / 256;

    k_invrank<<<blocksT, 256, 0, stream>>>(rank48_d, invrank_d);
    k_hashscatter<<<blocksK1, 256, 0, stream>>>(coords, rank48_d, fill, bitmap,
                                                sortedp, pkey, N);
    k_wprefix<<<NCOARSE, 256, 0, stream>>>(bitmap, wprefix, dtotal);
    k_meta<<<1, 256, 0, stream>>>(fill, dtotal, pointbase, gidbase, nvslot);
    k_sortbucket<<<NCOARSE, 256, 0, stream>>>(fill, pointbase, gidbase, sortedp,
                                              mlist, voxmeta);
    k_v2p<<<blocksN, 256, 0, stream>>>(pkey, bitmap, wprefix, gidbase, v2p, N);
    k_vox<<<blocksN, 256, 0, stream>>>(voxmeta, mlist, invrank_d, feats, nvslot,
                                       vox_feats, vox_coords, nvox, N);
}